// Round 2
// baseline (371.015 us; speedup 1.0000x reference)
//
#include <hip/hip_runtime.h>

#define K_DIM 1024
#define N_DIM 1024
#define GRID 256

typedef short v8s __attribute__((ext_vector_type(8)));
typedef float v4f __attribute__((ext_vector_type(4)));

__device__ __forceinline__ unsigned int bf16_rne(float f) {
    unsigned int u = __float_as_uint(f);
    u += 0x7FFFu + ((u >> 16) & 1u);
    return u >> 16;
}

// ---------- prep_w: fused column-norms + per-col constants + Btf build ----------
// Each block computes the column sum-of-squares for its 64 cols locally (wv is 4 MB,
// L2-resident), so no cross-block colss dependency, no memset, no extra dispatches.
__global__ void prep_w(const float* __restrict__ wv, const float* __restrict__ wg,
                       const float* __restrict__ bias, const float* __restrict__ cptr,
                       float* __restrict__ coshd, float* __restrict__ sinhd,
                       float* __restrict__ gfac, unsigned short* __restrict__ Btf) {
    __shared__ float tile[64 * 65];
    __shared__ float cred[4][64];
    __shared__ float cinv[64];
    const int t = threadIdx.x;
    const int ti = blockIdx.x & 15;   // k tile of 64
    const int tj = blockIdx.x >> 4;   // n tile of 64
    {   // local column sumsq over all 1024 rows for cols tj*64..+63
        const int cj = t & 63, rg = t >> 6;
        const float* wp = wv + (size_t)(rg * 256) * N_DIM + tj * 64 + cj;
        float ss = 0.f;
#pragma unroll 4
        for (int r = 0; r < 256; ++r) {
            float v = wp[(size_t)r * N_DIM];
            ss = fmaf(v, v, ss);
        }
        cred[rg][cj] = ss;
    }
    {   // load wv tile (ti,tj) into LDS
        const int kl = t >> 2, cq = t & 3;
        const float* src = wv + (size_t)(ti * 64 + kl) * N_DIM + tj * 64 + cq * 16;
        float4 fq[4];
#pragma unroll
        for (int i = 0; i < 4; ++i) fq[i] = ((const float4*)src)[i];
        float* dst = &tile[kl * 65 + cq * 16];
#pragma unroll
        for (int i = 0; i < 4; ++i) {
            dst[4 * i + 0] = fq[i].x; dst[4 * i + 1] = fq[i].y;
            dst[4 * i + 2] = fq[i].z; dst[4 * i + 3] = fq[i].w;
        }
    }
    __syncthreads();
    if (t < 64) {
        float s = cred[0][t] + cred[1][t] + cred[2][t] + cred[3][t];
        cinv[t] = 1.0f / fmaxf(sqrtf(s), 1e-15f);
        if (ti == 0) {
            const int col = tj * 64 + t;
            const float rc = sqrtf(cptr[0]);
            float d = 2.0f * rc * bias[col];
            float e = __expf(d), ie = 1.0f / e;
            coshd[col] = 0.5f * (e + ie);
            sinhd[col] = 0.5f * (e - ie);
            gfac[col] = 2.0f * wg[col];
        }
    }
    __syncthreads();
    {   // build Btf in MFMA B-fragment order
        const int nl = t & 63, kc = t >> 6;
        const float ci = cinv[nl];
        const int nt_g = tj * 4 + (nl >> 4);
#pragma unroll
        for (int h = 0; h < 2; ++h) {
            const int k8g = ti * 8 + kc * 2 + h;
            const int ks_g = k8g >> 2;
            const int L = (nl & 15) | ((k8g & 3) << 4);
            unsigned int p[4];
#pragma unroll
            for (int j = 0; j < 4; ++j) {
                float v0 = tile[(kc * 16 + h * 8 + 2 * j) * 65 + nl] * ci;
                float v1 = tile[(kc * 16 + h * 8 + 2 * j + 1) * 65 + nl] * ci;
                p[j] = bf16_rne(v0) | (bf16_rne(v1) << 16);
            }
            *(uint4*)(Btf + ((size_t)(nt_g * 32 + ks_g) * 64 + L) * 8) =
                make_uint4(p[0], p[1], p[2], p[3]);
        }
    }
}

// ---------- in-kernel A-panel staging: x (f32) -> bf16 MFMA fragments in LDS ----------
// Atom g (32B of x): row = g>>7, k8 = g&127 (8 k-values). Fragment slot:
// As[(mt*32+ks)*512 + (((lm ^ (ks&7)) | (qq<<4)))*8], mt=row>>4, lm=row&15,
// ks=k8>>2, qq=k8&3. XOR on lm spreads the ds_write_b128s across banks; the
// read side applies the same XOR (uniform per instr -> reads stay conflict-free).
// Per it, all 64 lanes of a wave hit one row -> full-wave shfl reduce for rowss.
__device__ __forceinline__ void stage_panel(const float* __restrict__ xp,
                                            unsigned short* __restrict__ Asl,
                                            float* __restrict__ rowssbuf, int t) {
#pragma unroll 2
    for (int it = 0; it < 16; ++it) {
        const int g = it * 512 + t;
        const int row = g >> 7, k8 = g & 127;
        const float4* fp = (const float4*)xp + (size_t)g * 2;
        float4 f0 = fp[0];
        float4 f1 = fp[1];
        float vals[8] = {f0.x, f0.y, f0.z, f0.w, f1.x, f1.y, f1.z, f1.w};
        unsigned int p[4];
        float ss = 0.f;
#pragma unroll
        for (int j = 0; j < 4; ++j) {
            ss = fmaf(vals[2 * j], vals[2 * j], ss);
            ss = fmaf(vals[2 * j + 1], vals[2 * j + 1], ss);
            p[j] = bf16_rne(vals[2 * j]) | (bf16_rne(vals[2 * j + 1]) << 16);
        }
        ss += __shfl_xor(ss, 1);  ss += __shfl_xor(ss, 2);  ss += __shfl_xor(ss, 4);
        ss += __shfl_xor(ss, 8);  ss += __shfl_xor(ss, 16); ss += __shfl_xor(ss, 32);
        if ((t & 63) == 0) atomicAdd(&rowssbuf[row], ss);
        const int mt = row >> 4, lm2 = row & 15, ks = k8 >> 2, qq = k8 & 3;
        const int idx = ((mt * 32 + ks) * 512) + (((lm2 ^ (ks & 7)) | (qq << 4)) * 8);
        *(uint4*)&Asl[idx] = make_uint4(p[0], p[1], p[2], p[3]);
    }
}

// ---------- persistent fused GEMM: grid=256 (1 block/CU), 2 panels of 64 rows ----------
// Stage of panel i+1 is issued right after panel i's K-loop ends, so its HBM latency
// hides under panel i's epilogue VALU; panel i's stores drain under panel i+1's K-loop.
__launch_bounds__(512, 2)
__global__ void gemm_fused(const float* __restrict__ x,
                           const unsigned short* __restrict__ Btf,
                           const float* __restrict__ cptr,
                           const float* __restrict__ coshd, const float* __restrict__ sinhd,
                           const float* __restrict__ gfac,
                           float* __restrict__ out, int panels) {
    __shared__ __align__(16) unsigned short As[4 * 32 * 512];   // 128 KiB
    __shared__ float s_rowss[2][64];
    __shared__ float s_rsum[64];

    const int t = threadIdx.x;
    const int w = t >> 6, L = t & 63;
    const int lm = L & 15, q = L >> 4;
    const int bm = blockIdx.x;

    const float cc = cptr[0];
    const float rc = sqrtf(cc);
    const float two_rc = 2.0f * rc;
    const float halfinvrc = 0.5f / rc;
    const float mn = (cc > 0.f) ? 0.996f / sqrtf(fmaxf(cc, 1e-15f)) : 1e15f;
    float ch[8], sh[8], gf[8];
#pragma unroll
    for (int n = 0; n < 8; ++n) {
        const int col = w * 128 + n * 16 + lm;
        ch[n] = coshd[col]; sh[n] = sinhd[col]; gf[n] = gfac[col];
    }

    const unsigned short* bw = Btf + (size_t)(w * 8) * 32 * 512 + (size_t)L * 8;

    // prologue: stage panel 0
    if (t < 64) s_rowss[0][t] = 0.f;
    __syncthreads();
    stage_panel(x + (size_t)bm * 64 * K_DIM, As, s_rowss[0], t);

#pragma unroll 1
    for (int i = 0; i < panels; ++i) {
        const int p = bm + i * GRID;
        const int pb = i & 1, nb = pb ^ 1;
        const bool more = (i + 1 < panels);
        __syncthreads();               // stage-end: As + rowss visible to all waves

        v4f acc[4][8];
#pragma unroll
        for (int a = 0; a < 4; ++a)
#pragma unroll
            for (int b = 0; b < 8; ++b) acc[a][b] = (v4f){0.f, 0.f, 0.f, 0.f};

        v8s bA[8], bB[8];
#pragma unroll
        for (int n = 0; n < 8; ++n)
            bA[n] = *(const v8s*)(bw + (n * 32) * 512);

#pragma unroll 1
        for (int kp = 0; kp < 16; ++kp) {
            const int k0 = kp * 2;
            // half 1: prefetch B(k0+1), compute k0 with bA
#pragma unroll
            for (int n = 0; n < 8; ++n)
                bB[n] = *(const v8s*)(bw + (n * 32 + k0 + 1) * 512);
            {
                const int lx = ((lm ^ (k0 & 7)) | (q << 4)) * 8;
                v8s a[4];
#pragma unroll
                for (int mt = 0; mt < 4; ++mt)
                    a[mt] = *(const v8s*)&As[(mt * 32 + k0) * 512 + lx];
                __builtin_amdgcn_s_setprio(1);
#pragma unroll
                for (int mt = 0; mt < 4; ++mt)
#pragma unroll
                    for (int n = 0; n < 8; ++n)
                        acc[mt][n] = __builtin_amdgcn_mfma_f32_16x16x32_bf16(
                            a[mt], bA[n], acc[mt][n], 0, 0, 0);
                __builtin_amdgcn_s_setprio(0);
            }
            // half 2: prefetch B(k0+2), compute k0+1 with bB
            if (kp < 15) {
#pragma unroll
                for (int n = 0; n < 8; ++n)
                    bA[n] = *(const v8s*)(bw + (n * 32 + k0 + 2) * 512);
            }
            {
                const int lx = ((lm ^ ((k0 + 1) & 7)) | (q << 4)) * 8;
                v8s a[4];
#pragma unroll
                for (int mt = 0; mt < 4; ++mt)
                    a[mt] = *(const v8s*)&As[(mt * 32 + k0 + 1) * 512 + lx];
                __builtin_amdgcn_s_setprio(1);
#pragma unroll
                for (int mt = 0; mt < 4; ++mt)
#pragma unroll
                    for (int n = 0; n < 8; ++n)
                        acc[mt][n] = __builtin_amdgcn_mfma_f32_16x16x32_bf16(
                            a[mt], bB[n], acc[mt][n], 0, 0, 0);
                __builtin_amdgcn_s_setprio(0);
            }
        }

        __syncthreads();               // K-end: all waves done reading As
        if (t < 64) { s_rsum[t] = 0.f; if (more) s_rowss[nb][t] = 0.f; }
        __syncthreads();               // zeros visible

        // stage next panel now: its global-load latency hides under the epilogue VALU
        if (more) stage_panel(x + (size_t)(p + GRID) * 64 * K_DIM, As, s_rowss[nb], t);

        // ---- epilogue: nonlinearity + in-block row reduce ----
        const float* rb = s_rowss[pb];
#pragma unroll
        for (int mt = 0; mt < 4; ++mt) {
            const int mloc = mt * 16 + q * 4;
            float sx[4];
#pragma unroll
            for (int rr = 0; rr < 4; ++rr) sx[rr] = cc * rb[mloc + rr];
            float rs[4] = {0.f, 0.f, 0.f, 0.f};
#pragma unroll
            for (int n = 0; n < 8; ++n) {
                v4f d = acc[mt][n];
#pragma unroll
                for (int rr = 0; rr < 4; ++rr) {
                    float cx2 = sx[rr];
                    float num = two_rc * d[rr] * ch[n] - (1.0f + cx2) * sh[n];
                    float den = fmaxf(1.0f - cx2, 1e-15f);
                    float tt = num * __builtin_amdgcn_rcpf(den);
                    float as_ = __logf(fabsf(tt) + sqrtf(fmaf(tt, tt, 1.0f)));
                    as_ = copysignf(as_, tt);
                    float u = gf[n] * as_;
                    float e = __expf(u);
                    float y = (e - __builtin_amdgcn_rcpf(e)) * halfinvrc;
                    d[rr] = y;
                    rs[rr] = fmaf(y, y, rs[rr]);
                }
                acc[mt][n] = d;
            }
#pragma unroll
            for (int rr = 0; rr < 4; ++rr) {
                float v = rs[rr];
                v += __shfl_xor(v, 1); v += __shfl_xor(v, 2);
                v += __shfl_xor(v, 4); v += __shfl_xor(v, 8);
                if (lm == 0) atomicAdd(&s_rsum[mloc + rr], v);
            }
        }
        __syncthreads();               // rsum complete (stage ds_writes also drained)

        // ---- fused projection scale + store ----
#pragma unroll
        for (int mt = 0; mt < 4; ++mt) {
            const int mloc = mt * 16 + q * 4;
            float f[4];
#pragma unroll
            for (int rr = 0; rr < 4; ++rr) {
                const float s = s_rsum[mloc + rr];
                const float scale = 1.0f / (1.0f + sqrtf(fmaf(cc, s, 1.0f)));
                const float nrm = fmaxf(sqrtf(s) * scale, 1e-15f);
                f[rr] = scale * (nrm > mn ? mn / nrm : 1.0f);
            }
#pragma unroll
            for (int rr = 0; rr < 4; ++rr) {
                float* op = out + (size_t)(p * 64 + mloc + rr) * N_DIM + w * 128 + lm;
#pragma unroll
                for (int n = 0; n < 8; ++n) op[n * 16] = acc[mt][n][rr] * f[rr];
            }
        }
    }
}

extern "C" void kernel_launch(void* const* d_in, const int* in_sizes, int n_in,
                              void* d_out, int out_size, void* d_ws, size_t ws_size,
                              hipStream_t stream) {
    const float* x    = (const float*)d_in[0];
    const float* wv   = (const float*)d_in[1];
    const float* wg   = (const float*)d_in[2];
    const float* bias = (const float*)d_in[3];
    const float* cptr = (const float*)d_in[4];
    float* out = (float*)d_out;

    const int OUT = in_sizes[2];            // 1024
    const int IN  = in_sizes[1] / OUT;      // 1024
    const int M   = in_sizes[0] / IN;       // 32768

    // ws layout: coshd[1024] | sinhd[1024] | gfac[1024] | Btf[IN*OUT]
    float* coshd = (float*)d_ws;
    float* sinhd = coshd + 1024;
    float* gfac  = sinhd + 1024;
    unsigned short* Btf = (unsigned short*)(gfac + 1024);

    prep_w<<<(IN / 64) * (OUT / 64), 256, 0, stream>>>(
        wv, wg, bias, cptr, coshd, sinhd, gfac, Btf);

    const int panels = (M / 64) / GRID;     // 2
    gemm_fused<<<GRID, 512, 0, stream>>>(
        x, Btf, cptr, coshd, sinhd, gfac, out, panels);
}

// Round 3
// 359.018 us; speedup vs baseline: 1.0334x; 1.0334x over previous
//
#include <hip/hip_runtime.h>

#define K_DIM 1024
#define N_DIM 1024
#define GRID 256

typedef short v8s __attribute__((ext_vector_type(8)));
typedef float v4f __attribute__((ext_vector_type(4)));
typedef unsigned int v4u __attribute__((ext_vector_type(4)));

__device__ __forceinline__ unsigned int bf16_rne(float f) {
    unsigned int u = __float_as_uint(f);
    u += 0x7FFFu + ((u >> 16) & 1u);
    return u >> 16;
}

// ---------- prep_w: fused column-norms + per-col constants + Btf build ----------
__global__ void prep_w(const float* __restrict__ wv, const float* __restrict__ wg,
                       const float* __restrict__ bias, const float* __restrict__ cptr,
                       float* __restrict__ coshd, float* __restrict__ sinhd,
                       float* __restrict__ gfac, unsigned short* __restrict__ Btf) {
    __shared__ float tile[64 * 65];
    __shared__ float cred[4][64];
    __shared__ float cinv[64];
    const int t = threadIdx.x;
    const int ti = blockIdx.x & 15;   // k tile of 64
    const int tj = blockIdx.x >> 4;   // n tile of 64
    {   // local column sumsq over all 1024 rows for cols tj*64..+63
        const int cj = t & 63, rg = t >> 6;
        const float* wp = wv + (size_t)(rg * 256) * N_DIM + tj * 64 + cj;
        float ss = 0.f;
#pragma unroll 4
        for (int r = 0; r < 256; ++r) {
            float v = wp[(size_t)r * N_DIM];
            ss = fmaf(v, v, ss);
        }
        cred[rg][cj] = ss;
    }
    {   // load wv tile (ti,tj) into LDS
        const int kl = t >> 2, cq = t & 3;
        const float* src = wv + (size_t)(ti * 64 + kl) * N_DIM + tj * 64 + cq * 16;
        float4 fq[4];
#pragma unroll
        for (int i = 0; i < 4; ++i) fq[i] = ((const float4*)src)[i];
        float* dst = &tile[kl * 65 + cq * 16];
#pragma unroll
        for (int i = 0; i < 4; ++i) {
            dst[4 * i + 0] = fq[i].x; dst[4 * i + 1] = fq[i].y;
            dst[4 * i + 2] = fq[i].z; dst[4 * i + 3] = fq[i].w;
        }
    }
    __syncthreads();
    if (t < 64) {
        float s = cred[0][t] + cred[1][t] + cred[2][t] + cred[3][t];
        cinv[t] = 1.0f / fmaxf(sqrtf(s), 1e-15f);
        if (ti == 0) {
            const int col = tj * 64 + t;
            const float rc = sqrtf(cptr[0]);
            float d = 2.0f * rc * bias[col];
            float e = __expf(d), ie = 1.0f / e;
            coshd[col] = 0.5f * (e + ie);
            sinhd[col] = 0.5f * (e - ie);
            gfac[col] = 2.0f * wg[col];
        }
    }
    __syncthreads();
    {   // build Btf in MFMA B-fragment order
        const int nl = t & 63, kc = t >> 6;
        const float ci = cinv[nl];
        const int nt_g = tj * 4 + (nl >> 4);
#pragma unroll
        for (int h = 0; h < 2; ++h) {
            const int k8g = ti * 8 + kc * 2 + h;
            const int ks_g = k8g >> 2;
            const int L = (nl & 15) | ((k8g & 3) << 4);
            unsigned int p[4];
#pragma unroll
            for (int j = 0; j < 4; ++j) {
                float v0 = tile[(kc * 16 + h * 8 + 2 * j) * 65 + nl] * ci;
                float v1 = tile[(kc * 16 + h * 8 + 2 * j + 1) * 65 + nl] * ci;
                p[j] = bf16_rne(v0) | (bf16_rne(v1) << 16);
            }
            *(uint4*)(Btf + ((size_t)(nt_g * 32 + ks_g) * 64 + L) * 8) =
                make_uint4(p[0], p[1], p[2], p[3]);
        }
    }
}

// ---------- A staging: x(f32) -> bf16 MFMA fragments in LDS ----------
// Slot swizzle S(lm,q,ks) = ((lm^ks^(q<<1))&7) | (lm&8) | (q<<4).
// Write side (row fixed, lanes vary ks,q): consecutive 8 lanes hit 8 distinct
// bank-groups (the q<<1 term breaks the old 4-way write conflict).
// Read side (ks fixed, lanes vary lm,q): bijective per instr -> conflict-free.
__device__ __forceinline__ void stage_panel(const float* __restrict__ xp,
                                            unsigned short* __restrict__ Asl,
                                            float* __restrict__ rowssbuf, int t) {
#pragma unroll 4
    for (int it = 0; it < 16; ++it) {
        const int g = it * 512 + t;
        const int row = g >> 7, k8 = g & 127;
        const float4* fp = (const float4*)xp + (size_t)g * 2;
        float4 f0 = fp[0];
        float4 f1 = fp[1];
        float vals[8] = {f0.x, f0.y, f0.z, f0.w, f1.x, f1.y, f1.z, f1.w};
        unsigned int p[4];
        float ss = 0.f;
#pragma unroll
        for (int j = 0; j < 4; ++j) {
            ss = fmaf(vals[2 * j], vals[2 * j], ss);
            ss = fmaf(vals[2 * j + 1], vals[2 * j + 1], ss);
            p[j] = bf16_rne(vals[2 * j]) | (bf16_rne(vals[2 * j + 1]) << 16);
        }
        ss += __shfl_xor(ss, 1);  ss += __shfl_xor(ss, 2);  ss += __shfl_xor(ss, 4);
        ss += __shfl_xor(ss, 8);  ss += __shfl_xor(ss, 16); ss += __shfl_xor(ss, 32);
        if ((t & 63) == 0) atomicAdd(&rowssbuf[row], ss);
        const int mt = row >> 4, lmr = row & 15, ks = k8 >> 2, qq = k8 & 3;
        const int S = ((lmr ^ ks ^ (qq << 1)) & 7) | (lmr & 8) | (qq << 4);
        const int idx = ((mt * 32 + ks) << 9) + (S << 3);
        *(uint4*)&Asl[idx] = make_uint4(p[0], p[1], p[2], p[3]);
    }
}

// ---------- K-loop building blocks (explicit vmcnt control, T4 pattern) ----------
__device__ __forceinline__ void bload8(v4u (&buf)[8], const unsigned short* bwu,
                                       const unsigned* voff, int k) {
    const char* sb = (const char*)bwu + (size_t)k * 1024;
#pragma unroll
    for (int n = 0; n < 8; ++n)
        asm volatile("global_load_dwordx4 %0, %1, %2"
                     : "=v"(buf[n]) : "v"(voff[n]), "s"(sb));
}

__device__ __forceinline__ void aread4(v8s (&ab)[4], const unsigned short* As,
                                       int cl, int rb, int k) {
    const int off = (((cl ^ (k & 7)) << 4) | rb);
#pragma unroll
    for (int mt = 0; mt < 4; ++mt)
        ab[mt] = *(const v8s*)((const char*)As + ((mt * 32 + k) << 10) + off);
}

__device__ __forceinline__ void mmac(v4f (&acc)[4][8], const v8s (&a)[4],
                                     const v4u (&b)[8]) {
    __builtin_amdgcn_s_setprio(1);
#pragma unroll
    for (int mt = 0; mt < 4; ++mt)
#pragma unroll
        for (int n = 0; n < 8; ++n)
            acc[mt][n] = __builtin_amdgcn_mfma_f32_16x16x32_bf16(
                a[mt], __builtin_bit_cast(v8s, b[n]), acc[mt][n], 0, 0, 0);
    __builtin_amdgcn_s_setprio(0);
}

// counted wait: previous batch (8 oldest) must land; in-flight prefetch (8) stays out.
// sched_barrier(0) right after: hipcc hoists MFMA past asm waitcnt otherwise (rule #18).
#define WAITV8 do { asm volatile("s_waitcnt vmcnt(8)"); __builtin_amdgcn_sched_barrier(0); } while (0)
#define WAITV0 do { asm volatile("s_waitcnt vmcnt(0)"); __builtin_amdgcn_sched_barrier(0); } while (0)

// ---------- persistent fused GEMM: grid=256 (1 block/CU), panels of 64 rows ----------
__launch_bounds__(512, 2)
__global__ void gemm_fused(const float* __restrict__ x,
                           const unsigned short* __restrict__ Btf,
                           const float* __restrict__ cptr,
                           const float* __restrict__ coshd, const float* __restrict__ sinhd,
                           const float* __restrict__ gfac,
                           float* __restrict__ out, int panels) {
    __shared__ __align__(16) unsigned short As[4 * 32 * 512];   // 128 KiB
    __shared__ float s_rowss[2][64];
    __shared__ float s_rsum[64];

    const int t = threadIdx.x;
    const int w = t >> 6, L = t & 63;
    const int lm = L & 15, q = L >> 4;
    const int bm = blockIdx.x;

    // swizzled A-read lane constants
    const int cl = (lm & 7) ^ ((q << 1) & 7);
    const int rb = ((lm & 8) << 4) + (q << 8);

    const float cc = cptr[0];
    const float rc = sqrtf(cc);
    const float two_rc = 2.0f * rc;
    const float halfinvrc = 0.5f / rc;
    const float mn = (cc > 0.f) ? 0.996f / sqrtf(fmaxf(cc, 1e-15f)) : 1e15f;
    float ch[8], sh[8], gf[8];
#pragma unroll
    for (int n = 0; n < 8; ++n) {
        const int col = w * 128 + n * 16 + lm;
        ch[n] = coshd[col]; sh[n] = sinhd[col]; gf[n] = gfac[col];
    }

    // wave-uniform B base (SGPR) + per-lane 32-bit voffsets for asm loads
    const int wu = __builtin_amdgcn_readfirstlane(w);
    const unsigned short* bwu = Btf + (size_t)wu * 131072;   // wu*8*32*512
    unsigned voff[8];
#pragma unroll
    for (int n = 0; n < 8; ++n) voff[n] = (unsigned)(L * 16 + n * 32768);

    // prologue: stage panel 0
    if (t < 64) s_rowss[0][t] = 0.f;
    __syncthreads();
    stage_panel(x + (size_t)bm * 64 * K_DIM, As, s_rowss[0], t);

#pragma unroll 1
    for (int i = 0; i < panels; ++i) {
        const int p = bm + i * GRID;
        const int pb = i & 1, nb = pb ^ 1;
        const bool more = (i + 1 < panels);
        __syncthreads();   // stage-end: As + rowss visible; also drains vmcnt for counting

        v4f acc[4][8];
#pragma unroll
        for (int a = 0; a < 4; ++a)
#pragma unroll
            for (int b = 0; b < 8; ++b) acc[a][b] = (v4f){0.f, 0.f, 0.f, 0.f};

        v4u b0[8], b1[8];
        v8s a0[4], a1[4];
        bload8(b0, bwu, voff, 0);
        bload8(b1, bwu, voff, 1);
        aread4(a0, As, cl, rb, 0);

#pragma unroll 1
        for (int kp = 0; kp < 15; ++kp) {
            const int k = kp * 2;
            aread4(a1, As, cl, rb, k + 1);
            WAITV8;
            mmac(acc, a0, b0);
            bload8(b0, bwu, voff, k + 2);
            aread4(a0, As, cl, rb, k + 2);
            WAITV8;
            mmac(acc, a1, b1);
            bload8(b1, bwu, voff, k + 3);
        }
        aread4(a1, As, cl, rb, 31);
        WAITV8;
        mmac(acc, a0, b0);
        WAITV0;
        mmac(acc, a1, b1);

        __syncthreads();   // K-end: all waves done reading As
        if (t < 64) { s_rsum[t] = 0.f; if (more) s_rowss[nb][t] = 0.f; }
        __syncthreads();

        // stage next panel now: HBM latency hides under the epilogue VALU
        if (more) stage_panel(x + (size_t)(p + GRID) * 64 * K_DIM, As, s_rowss[nb], t);

        // ---- epilogue: nonlinearity + in-block row reduce ----
        const float* rbuf = s_rowss[pb];
#pragma unroll
        for (int mt = 0; mt < 4; ++mt) {
            const int mloc = mt * 16 + q * 4;
            float sx[4];
#pragma unroll
            for (int rr = 0; rr < 4; ++rr) sx[rr] = cc * rbuf[mloc + rr];
            float rs[4] = {0.f, 0.f, 0.f, 0.f};
#pragma unroll
            for (int n = 0; n < 8; ++n) {
                v4f d = acc[mt][n];
#pragma unroll
                for (int rr = 0; rr < 4; ++rr) {
                    float cx2 = sx[rr];
                    float num = two_rc * d[rr] * ch[n] - (1.0f + cx2) * sh[n];
                    float den = fmaxf(1.0f - cx2, 1e-15f);
                    float tt = num * __builtin_amdgcn_rcpf(den);
                    float as_ = __logf(fabsf(tt) + sqrtf(fmaf(tt, tt, 1.0f)));
                    as_ = copysignf(as_, tt);
                    float u = gf[n] * as_;
                    float e = __expf(u);
                    float y = (e - __builtin_amdgcn_rcpf(e)) * halfinvrc;
                    d[rr] = y;
                    rs[rr] = fmaf(y, y, rs[rr]);
                }
                acc[mt][n] = d;
            }
#pragma unroll
            for (int rr = 0; rr < 4; ++rr) {
                float v = rs[rr];
                v += __shfl_xor(v, 1); v += __shfl_xor(v, 2);
                v += __shfl_xor(v, 4); v += __shfl_xor(v, 8);
                if (lm == 0) atomicAdd(&s_rsum[mloc + rr], v);
            }
        }
        __syncthreads();   // rsum complete (next-panel stage ds_writes also drained)

        // ---- fused projection scale + store ----
#pragma unroll
        for (int mt = 0; mt < 4; ++mt) {
            const int mloc = mt * 16 + q * 4;
            float f[4];
#pragma unroll
            for (int rr = 0; rr < 4; ++rr) {
                const float s = s_rsum[mloc + rr];
                const float scale = 1.0f / (1.0f + sqrtf(fmaf(cc, s, 1.0f)));
                const float nrm = fmaxf(sqrtf(s) * scale, 1e-15f);
                f[rr] = scale * (nrm > mn ? mn / nrm : 1.0f);
            }
#pragma unroll
            for (int rr = 0; rr < 4; ++rr) {
                float* op = out + (size_t)(p * 64 + mloc + rr) * N_DIM + w * 128 + lm;
#pragma unroll
                for (int n = 0; n < 8; ++n) op[n * 16] = acc[mt][n][rr] * f[rr];
            }
        }
    }
}

extern "C" void kernel_launch(void* const* d_in, const int* in_sizes, int n_in,
                              void* d_out, int out_size, void* d_ws, size_t ws_size,
                              hipStream_t stream) {
    const float* x    = (const float*)d_in[0];
    const float* wv   = (const float*)d_in[1];
    const float* wg   = (const float*)d_in[2];
    const float* bias = (const float*)d_in[3];
    const float* cptr = (const float*)d_in[4];
    float* out = (float*)d_out;

    const int OUT = in_sizes[2];            // 1024
    const int IN  = in_sizes[1] / OUT;      // 1024
    const int M   = in_sizes[0] / IN;       // 32768

    // ws layout: coshd[1024] | sinhd[1024] | gfac[1024] | Btf[IN*OUT]
    float* coshd = (float*)d_ws;
    float* sinhd = coshd + 1024;
    float* gfac  = sinhd + 1024;
    unsigned short* Btf = (unsigned short*)(gfac + 1024);

    prep_w<<<(IN / 64) * (OUT / 64), 256, 0, stream>>>(
        wv, wg, bias, cptr, coshd, sinhd, gfac, Btf);

    const int panels = (M / 64) / GRID;     // 2
    gemm_fused<<<GRID, 512, 0, stream>>>(
        x, Btf, cptr, coshd, sinhd, gfac, out, panels);
}

// Round 5
// 355.143 us; speedup vs baseline: 1.0447x; 1.0109x over previous
//
#include <hip/hip_runtime.h>

#define K_DIM 1024
#define N_DIM 1024

typedef short v8s __attribute__((ext_vector_type(8)));
typedef float v4f __attribute__((ext_vector_type(4)));

__device__ __forceinline__ unsigned int bf16_rne(float f) {
    unsigned int u = __float_as_uint(f);
    u += 0x7FFFu + ((u >> 16) & 1u);
    return u >> 16;
}

// ---------- prep_w: fused column-norms + per-col constants + Btf build ----------
__global__ void prep_w(const float* __restrict__ wv, const float* __restrict__ wg,
                       const float* __restrict__ bias, const float* __restrict__ cptr,
                       float* __restrict__ coshd, float* __restrict__ sinhd,
                       float* __restrict__ gfac, unsigned short* __restrict__ Btf) {
    __shared__ float tile[64 * 65];
    __shared__ float cred[4][64];
    __shared__ float cinv[64];
    const int t = threadIdx.x;
    const int ti = blockIdx.x & 15;   // k tile of 64
    const int tj = blockIdx.x >> 4;   // n tile of 64
    {   // local column sumsq over all 1024 rows for cols tj*64..+63
        // unroll 16: 16 independent loads in flight per thread (was 4 -> latency chain)
        const int cj = t & 63, rg = t >> 6;
        const float* wp = wv + (size_t)(rg * 256) * N_DIM + tj * 64 + cj;
        float ss = 0.f;
#pragma unroll 16
        for (int r = 0; r < 256; ++r) {
            float v = wp[(size_t)r * N_DIM];
            ss = fmaf(v, v, ss);
        }
        cred[rg][cj] = ss;
    }
    {   // load wv tile (ti,tj) into LDS
        const int kl = t >> 2, cq = t & 3;
        const float* src = wv + (size_t)(ti * 64 + kl) * N_DIM + tj * 64 + cq * 16;
        float4 fq[4];
#pragma unroll
        for (int i = 0; i < 4; ++i) fq[i] = ((const float4*)src)[i];
        float* dst = &tile[kl * 65 + cq * 16];
#pragma unroll
        for (int i = 0; i < 4; ++i) {
            dst[4 * i + 0] = fq[i].x; dst[4 * i + 1] = fq[i].y;
            dst[4 * i + 2] = fq[i].z; dst[4 * i + 3] = fq[i].w;
        }
    }
    __syncthreads();
    if (t < 64) {
        float s = cred[0][t] + cred[1][t] + cred[2][t] + cred[3][t];
        cinv[t] = 1.0f / fmaxf(sqrtf(s), 1e-15f);
        if (ti == 0) {
            const int col = tj * 64 + t;
            const float rc = sqrtf(cptr[0]);
            float d = 2.0f * rc * bias[col];
            float e = __expf(d), ie = 1.0f / e;
            coshd[col] = 0.5f * (e + ie);
            sinhd[col] = 0.5f * (e - ie);
            gfac[col] = 2.0f * wg[col];
        }
    }
    __syncthreads();
    {   // build Btf in MFMA B-fragment order
        const int nl = t & 63, kc = t >> 6;
        const float ci = cinv[nl];
        const int nt_g = tj * 4 + (nl >> 4);
#pragma unroll
        for (int h = 0; h < 2; ++h) {
            const int k8g = ti * 8 + kc * 2 + h;
            const int ks_g = k8g >> 2;
            const int L = (nl & 15) | ((k8g & 3) << 4);
            unsigned int p[4];
#pragma unroll
            for (int j = 0; j < 4; ++j) {
                float v0 = tile[(kc * 16 + h * 8 + 2 * j) * 65 + nl] * ci;
                float v1 = tile[(kc * 16 + h * 8 + 2 * j + 1) * 65 + nl] * ci;
                p[j] = bf16_rne(v0) | (bf16_rne(v1) << 16);
            }
            *(uint4*)(Btf + ((size_t)(nt_g * 32 + ks_g) * 64 + L) * 8) =
                make_uint4(p[0], p[1], p[2], p[3]);
        }
    }
}

// ---------- fused GEMM: 64 rows x ALL 1024 cols per block, 16 waves ----------
// 1024 thr = 16 waves (4/SIMD with the 128-VGPR cap: acc is only 2x8 v4f = 64).
// Wave (wm,wn): rows wm*32 + mt*16, cols wn*128 + n*16. A panel staged in-kernel
// from f32 x straight into MFMA-fragment order (lane-linear ds_write_b128, no
// swizzle needed on either side). B fragments stream global->VGPR from the
// L2-resident Btf; no barriers in the K-loop -- 4 waves/SIMD hide the latency.
__launch_bounds__(1024, 4)
__global__ void gemm_fused(const float* __restrict__ x,
                           const unsigned short* __restrict__ Btf,
                           const float* __restrict__ cptr,
                           const float* __restrict__ coshd, const float* __restrict__ sinhd,
                           const float* __restrict__ gfac,
                           float* __restrict__ out) {
    __shared__ __align__(16) unsigned short As[4 * 32 * 64 * 8];   // 128 KiB
    __shared__ float s_rowss[64];
    __shared__ float s_rsum[64];

    const int t = threadIdx.x;
    const int w = t >> 6, L = t & 63;
    const int lm = L & 15, q = L >> 4;
    const int wm = w >> 3, wn = w & 7;
    const int bm = blockIdx.x;
    const int r0 = bm * 64;

    if (t < 64) { s_rowss[t] = 0.f; s_rsum[t] = 0.f; }
    __syncthreads();

    // ---- stage A panel: 128 fragment-blocks of 1 KiB, 8 per wave ----
    // flat = (mtg*32 + s); lane L holds x[r0 + mtg*16 + lm][s*32 + q*8 + 0..7]
#pragma unroll
    for (int i = 0; i < 8; ++i) {
        const int flat = w + i * 16;           // 0..127
        const int mtg = flat >> 5, s = flat & 31;
        const float* xp = x + (size_t)(r0 + mtg * 16 + lm) * K_DIM + s * 32 + q * 8;
        float4 f0 = ((const float4*)xp)[0];
        float4 f1 = ((const float4*)xp)[1];
        float vals[8] = {f0.x, f0.y, f0.z, f0.w, f1.x, f1.y, f1.z, f1.w};
        unsigned int p[4];
        float ss = 0.f;
#pragma unroll
        for (int j = 0; j < 4; ++j) {
            ss = fmaf(vals[2 * j], vals[2 * j], ss);
            ss = fmaf(vals[2 * j + 1], vals[2 * j + 1], ss);
            p[j] = bf16_rne(vals[2 * j]) | (bf16_rne(vals[2 * j + 1]) << 16);
        }
        *(uint4*)&As[(size_t)(flat * 64 + L) * 8] = make_uint4(p[0], p[1], p[2], p[3]);
        // row sumsq: lanes L, L+16, L+32, L+48 share row mtg*16+lm
        ss += __shfl_xor(ss, 16); ss += __shfl_xor(ss, 32);
        if (q == 0) atomicAdd(&s_rowss[mtg * 16 + lm], ss);
    }
    __syncthreads();

    // ---- K loop: 32 slices, 16 MFMA each, no barriers ----
    v4f acc[2][8];
#pragma unroll
    for (int a = 0; a < 2; ++a)
#pragma unroll
        for (int b = 0; b < 8; ++b) acc[a][b] = (v4f){0.f, 0.f, 0.f, 0.f};

    const unsigned short* bbase = Btf + (size_t)(wn * 8) * 16384 + (size_t)L * 8;
    const unsigned short* abase0 = As + (size_t)(wm * 2) * 16384 + (size_t)L * 8;
    const unsigned short* abase1 = abase0 + 16384;

#pragma unroll 1
    for (int s = 0; s < 32; ++s) {
        v8s b[8];
#pragma unroll
        for (int j = 0; j < 8; ++j)
            b[j] = *(const v8s*)(bbase + (size_t)j * 16384 + s * 512);
        v8s a0 = *(const v8s*)(abase0 + s * 512);
        v8s a1 = *(const v8s*)(abase1 + s * 512);
        __builtin_amdgcn_s_setprio(1);
#pragma unroll
        for (int n = 0; n < 8; ++n)
            acc[0][n] = __builtin_amdgcn_mfma_f32_16x16x32_bf16(a0, b[n], acc[0][n], 0, 0, 0);
#pragma unroll
        for (int n = 0; n < 8; ++n)
            acc[1][n] = __builtin_amdgcn_mfma_f32_16x16x32_bf16(a1, b[n], acc[1][n], 0, 0, 0);
        __builtin_amdgcn_s_setprio(0);
    }

    // ---- epilogue: nonlinearity + in-block row reduce ----
    const float cc = cptr[0];
    const float rc = sqrtf(cc);
    const float two_rc = 2.0f * rc;
    const float halfinvrc = 0.5f / rc;
    const float mn = (cc > 0.f) ? 0.996f / sqrtf(fmaxf(cc, 1e-15f)) : 1e15f;
    float ch[8], sh[8], gf[8];
#pragma unroll
    for (int n = 0; n < 8; ++n) {
        const int col = wn * 128 + n * 16 + lm;
        ch[n] = coshd[col]; sh[n] = sinhd[col]; gf[n] = gfac[col];
    }

#pragma unroll
    for (int mt = 0; mt < 2; ++mt) {
        const int mloc = wm * 32 + mt * 16 + q * 4;
        float sx[4];
#pragma unroll
        for (int rr = 0; rr < 4; ++rr) sx[rr] = cc * s_rowss[mloc + rr];
        float rs[4] = {0.f, 0.f, 0.f, 0.f};
#pragma unroll
        for (int n = 0; n < 8; ++n) {
            v4f d = acc[mt][n];
#pragma unroll
            for (int rr = 0; rr < 4; ++rr) {
                float cx2 = sx[rr];
                float num = two_rc * d[rr] * ch[n] - (1.0f + cx2) * sh[n];
                float den = fmaxf(1.0f - cx2, 1e-15f);
                float tt = num * __builtin_amdgcn_rcpf(den);
                float as_ = __logf(fabsf(tt) + sqrtf(fmaf(tt, tt, 1.0f)));
                as_ = copysignf(as_, tt);
                float u = gf[n] * as_;
                float e = __expf(u);
                float y = (e - __builtin_amdgcn_rcpf(e)) * halfinvrc;
                d[rr] = y;
                rs[rr] = fmaf(y, y, rs[rr]);
            }
            acc[mt][n] = d;
        }
#pragma unroll
        for (int rr = 0; rr < 4; ++rr) {
            float v = rs[rr];
            v += __shfl_xor(v, 1); v += __shfl_xor(v, 2);
            v += __shfl_xor(v, 4); v += __shfl_xor(v, 8);
            if (lm == 0) atomicAdd(&s_rsum[mloc + rr], v);
        }
    }
    __syncthreads();

    // ---- fused projection scale + store ----
#pragma unroll
    for (int mt = 0; mt < 2; ++mt) {
        const int mloc = wm * 32 + mt * 16 + q * 4;
        float f[4];
#pragma unroll
        for (int rr = 0; rr < 4; ++rr) {
            const float s = s_rsum[mloc + rr];
            const float scale = 1.0f / (1.0f + sqrtf(fmaf(cc, s, 1.0f)));
            const float nrm = fmaxf(sqrtf(s) * scale, 1e-15f);
            f[rr] = scale * (nrm > mn ? mn / nrm : 1.0f);
        }
#pragma unroll
        for (int rr = 0; rr < 4; ++rr) {
            float* op = out + (size_t)(r0 + mloc + rr) * N_DIM + wn * 128 + lm;
#pragma unroll
            for (int n = 0; n < 8; ++n) op[n * 16] = acc[mt][n][rr] * f[rr];
        }
    }
}

extern "C" void kernel_launch(void* const* d_in, const int* in_sizes, int n_in,
                              void* d_out, int out_size, void* d_ws, size_t ws_size,
                              hipStream_t stream) {
    const float* x    = (const float*)d_in[0];
    const float* wv   = (const float*)d_in[1];
    const float* wg   = (const float*)d_in[2];
    const float* bias = (const float*)d_in[3];
    const float* cptr = (const float*)d_in[4];
    float* out = (float*)d_out;

    const int OUT = in_sizes[2];            // 1024
    const int IN  = in_sizes[1] / OUT;      // 1024
    const int M   = in_sizes[0] / IN;       // 32768

    // ws layout: coshd[1024] | sinhd[1024] | gfac[1024] | Btf[IN*OUT]
    float* coshd = (float*)d_ws;
    float* sinhd = coshd + 1024;
    float* gfac  = sinhd + 1024;
    unsigned short* Btf = (unsigned short*)(gfac + 1024);

    prep_w<<<(IN / 64) * (OUT / 64), 256, 0, stream>>>(
        wv, wg, bias, cptr, coshd, sinhd, gfac, Btf);

    gemm_fused<<<M / 64, 1024, 0, stream>>>(
        x, Btf, cptr, coshd, sinhd, gfac, out);
}